// Round 13
// baseline (177.023 us; speedup 1.0000x reference)
//
#include <hip/hip_runtime.h>

#define BB 128
#define LL 256
#define DD 384
#define QB 64

typedef __attribute__((ext_vector_type(8))) _Float16 half8;
typedef __attribute__((ext_vector_type(4))) _Float16 half4;
typedef __attribute__((ext_vector_type(4))) float f32x4;

__device__ inline uint packrtz(float a, float b) {
  auto h = __builtin_amdgcn_cvt_pkrtz(a, b);
  return __builtin_bit_cast(uint, h);
}

__device__ inline half4 cvt4(f32x4 a) {
  uint2 u = make_uint2(packrtz(a[0], a[1]), packrtz(a[2], a[3]));
  return __builtin_bit_cast(half4, u);
}

__device__ inline half4 ld4h(const short* p) {   // 8B LDS read
  uint2 v = *(const uint2*)p;
  return __builtin_bit_cast(half4, v);
}

#define MFMAK16 __builtin_amdgcn_mfma_f32_16x16x16f16

typedef const __attribute__((address_space(1))) uint ga_uint;
typedef __attribute__((address_space(3))) uint ls_uint;

// One block per (batch, side, 64-row tile). 512 threads = 8 waves, wave-grid 1x8.
// LDS 51KB -> 3 blocks/CU (the experiment: occupancy 2->3 blocks).
__global__ __launch_bounds__(512, 6) void fused_kernel(
    const float* __restrict__ qf, const float* __restrict__ af,
    const int* __restrict__ qm, const int* __restrict__ am,
    float* __restrict__ accum)
{
  // XCD-affine decode: xcd = bid&7 = b&7 -> all 8 tiles of a batch on one XCD
  const int bid = blockIdx.x;
  const int blo = bid & 7, r1 = bid >> 3;
  const int tl = r1 & 7, bhi = r1 >> 3;
  const int b = bhi * 8 + blo;
  const int side = tl >> 2, r0 = (tl & 3) * QB;

  const float* self = side ? af : qf;   // rows we attend FROM
  const float* feat = side ? qf : af;   // rows we attend TO
  const int*   msk  = side ? am : qm;

  // 48128B union:
  //   Phase A: feat fp32 dbuf 2x16KB at [0,32768); self fp32 dbuf 2x4KB at [32768,40960)
  //   Post-A : sAl (P fp16, frag layout) [0,32768); sVt fp16 [384][20] at [32768,48128)
  __shared__ __align__(16) char sUnion[48128];
  __shared__ float sRedM[8][QB];      // softmax max partials; epilogue l2 partials
  __shared__ float sOv[512];          // softmax sum partials | epilogue pool/inv/ssq

  float* sStageF = (float*)sUnion;
  float* sStageS = (float*)(sUnion + 32768);
  short* sAl     = (short*)sUnion;
  short (*sVt)[20] = (short(*)[20])(sUnion + 32768);
  float (*sRedS)[QB] = (float(*)[QB])sOv;
  float* sPool = sOv;          // [0,384)
  float* sInv  = sOv + 384;    // [384,448)
  float* sSsq  = sOv + 448;    // [448,512)

  const int t = threadIdx.x;
  const int w = t >> 6, lane = t & 63;
  const int lam = lane & 15, g = lane >> 4;

  const float* selfb = self + ((size_t)b * LL + r0) * DD;
  const float* featb = feat + (size_t)b * LL * DD;

  // ---------------- Phase A: K=16 chunks, gll dbuf, 1 barrier/chunk ----------------
  // gll dest linear; source granule pre-swizzled: lane l supplies logical granule
  // (l&3)^((l>>3)&3) of row base+(l>>2). Read: logical g lives at phys g^((lam>>1)&3).
  const int lg16 = ((lane & 3) ^ ((lane >> 3) & 3)) * 4;
  const int lrow = lane >> 2;
  const int key  = (lam >> 1) & 3;

  #define STAGE16(kc_, bi_) do {                                                  \
    const int k0_ = (kc_) * 16;                                                   \
    _Pragma("unroll")                                                             \
    for (int i = 0; i < 2; ++i) {                                                 \
      int R = w * 32 + i * 16;                                                    \
      __builtin_amdgcn_global_load_lds(                                           \
          (ga_uint*)&featb[(size_t)(R + lrow) * DD + k0_ + lg16],                 \
          (ls_uint*)&sStageF[(bi_) * 4096 + R * 16], 16, 0, 0);                   \
    }                                                                             \
    if (w < 4) {                                                                  \
      int R = w * 16;                                                             \
      __builtin_amdgcn_global_load_lds(                                           \
          (ga_uint*)&selfb[(size_t)(R + lrow) * DD + k0_ + lg16],                 \
          (ls_uint*)&sStageS[(bi_) * 1024 + R * 16], 16, 0, 0);                   \
    }                                                                             \
  } while (0)

  f32x4 accS[4][2] = {};
  STAGE16(0, 0);
  __syncthreads();
  for (int kc = 0; kc < 24; ++kc) {
    const int cur = kc & 1;
    if (kc < 23) STAGE16(kc + 1, cur ^ 1);
    half4 ah[4], bh[2];
    #pragma unroll
    for (int rt = 0; rt < 4; ++rt)
      ah[rt] = cvt4(*(const f32x4*)&sStageS[cur * 1024 + (rt * 16 + lam) * 16 + ((g ^ key) << 2)]);
    #pragma unroll
    for (int ct = 0; ct < 2; ++ct)
      bh[ct] = cvt4(*(const f32x4*)&sStageF[cur * 4096 + (w * 32 + ct * 16 + lam) * 16 + ((g ^ key) << 2)]);
    #pragma unroll
    for (int rt = 0; rt < 4; ++rt)
      #pragma unroll
      for (int ct = 0; ct < 2; ++ct)
        accS[rt][ct] = MFMAK16(ah[rt], bh[ct], accS[rt][ct], 0, 0, 0);
    __syncthreads();
  }

  // ---------------- Softmax over cols (C layout: col=lane&15, row=g*4+rg) ----------------
  #pragma unroll
  for (int rt = 0; rt < 4; ++rt)
    #pragma unroll
    for (int rg = 0; rg < 4; ++rg) {
      float m = fmaxf(accS[rt][0][rg], accS[rt][1][rg]);
      #pragma unroll
      for (int off = 1; off < 16; off <<= 1) m = fmaxf(m, __shfl_xor(m, off));
      if (lam == 0) sRedM[w][rt * 16 + g * 4 + rg] = m;
    }
  __syncthreads();
  #pragma unroll
  for (int rt = 0; rt < 4; ++rt)
    #pragma unroll
    for (int rg = 0; rg < 4; ++rg) {
      int row = rt * 16 + g * 4 + rg;
      float m = sRedM[0][row];
      #pragma unroll
      for (int ww = 1; ww < 8; ++ww) m = fmaxf(m, sRedM[ww][row]);
      float s = 0.f;
      #pragma unroll
      for (int ct = 0; ct < 2; ++ct) {
        float p = __expf(accS[rt][ct][rg] - m);
        accS[rt][ct][rg] = p;
        s += p;
      }
      #pragma unroll
      for (int off = 1; off < 16; off <<= 1) s += __shfl_xor(s, off);
      if (lam == 0) sRedS[w][row] = s;
    }
  __syncthreads();
  #pragma unroll
  for (int rt = 0; rt < 4; ++rt)
    #pragma unroll
    for (int rg = 0; rg < 4; ++rg) {
      int row = rt * 16 + g * 4 + rg;
      float s = 0.f;
      #pragma unroll
      for (int ww = 0; ww < 8; ++ww) s += sRedS[ww][row];
      float inv = 1.f / s;
      #pragma unroll
      for (int ct = 0; ct < 2; ++ct) {
        int c = w * 32 + ct * 16 + lam;
        _Float16 ph = (_Float16)(accS[rt][ct][rg] * inv);
        sAl[((c >> 3) * QB + row) * 8 + (c & 7)] =
            (short)__builtin_bit_cast(unsigned short, ph);
      }
    }
  __syncthreads();

  // ---------------- PV: O[64][384] = P @ feat, K=16 chunks (16 tokens) ----------------
  // wave w: d-cols w*48 + dt*16 + lam (dt=0..2)
  int gofs[6];
  short* wp[6];
  #pragma unroll
  for (int i = 0; i < 6; ++i) {
    int u = t + i * 512;           // 3072 slots: token-pair tp x dim d
    int tp = u / 384, d = u - tp * 384;
    gofs[i] = tp * 2 * DD + d;
    wp[i] = &sVt[d][tp * 2];
  }

  float v0[6], v1[6];
  #define LOADV(ac_) do {                                                          \
    const int kb_ = (ac_) * 16 * DD;                                               \
    _Pragma("unroll")                                                              \
    for (int i = 0; i < 6; ++i) {                                                  \
      const float* fp = &featb[kb_ + gofs[i]];                                     \
      v0[i] = fp[0];                                                               \
      v1[i] = fp[DD];                                                              \
    }                                                                              \
  } while (0)

  f32x4 accP[4][3] = {};
  LOADV(0);
  for (int ac = 0; ac < 16; ++ac) {
    #pragma unroll
    for (int i = 0; i < 6; ++i)
      *(uint*)wp[i] = packrtz(v0[i], v1[i]);
    __syncthreads();
    if (ac < 15) LOADV(ac + 1);
    half4 pf[4], vf[3];
    #pragma unroll
    for (int rt = 0; rt < 4; ++rt)
      pf[rt] = ld4h(&sAl[((ac * 2 + (g >> 1)) * QB + rt * 16 + lam) * 8 + (g & 1) * 4]);
    #pragma unroll
    for (int dt = 0; dt < 3; ++dt)
      vf[dt] = ld4h(&sVt[w * 48 + dt * 16 + lam][g * 4]);
    #pragma unroll
    for (int rt = 0; rt < 4; ++rt)
      #pragma unroll
      for (int dt = 0; dt < 3; ++dt)
        accP[rt][dt] = MFMAK16(pf[rt], vf[dt], accP[rt][dt], 0, 0, 0);
    __syncthreads();
  }

  // ---------------- Epilogue: row l2norm over [self|attended], masked pool ----------------
  #pragma unroll
  for (int rt = 0; rt < 4; ++rt)
    #pragma unroll
    for (int rg = 0; rg < 4; ++rg) {
      float s = 0.f;
      #pragma unroll
      for (int dt = 0; dt < 3; ++dt) s += accP[rt][dt][rg] * accP[rt][dt][rg];
      #pragma unroll
      for (int off = 1; off < 16; off <<= 1) s += __shfl_xor(s, off);
      if (lam == 0) sRedM[w][rt * 16 + g * 4 + rg] = s;
    }
  {
    int sr = t >> 3, sc = (t & 7) * 4;
    const float* sp = &selfb[(size_t)sr * DD];
    float ss = 0.f;
    #pragma unroll
    for (int j = 0; j < 12; ++j) {
      float4 v = *(const float4*)&sp[sc + j * 32];
      ss += v.x * v.x + v.y * v.y + v.z * v.z + v.w * v.w;
    }
    ss += __shfl_xor(ss, 1); ss += __shfl_xor(ss, 2); ss += __shfl_xor(ss, 4);
    if ((t & 7) == 0) sSsq[sr] = ss;
  }
  __syncthreads();
  if (t < QB) {
    float tot = sSsq[t];
    #pragma unroll
    for (int ww = 0; ww < 8; ++ww) tot += sRedM[ww][t];
    int mv = msk[(size_t)b * LL + r0 + t];
    sInv[t] = mv ? (1.f / fmaxf(sqrtf(tot), 1e-12f)) : 0.f;
  }
  __syncthreads();
  #pragma unroll
  for (int dt = 0; dt < 3; ++dt) {
    float pa = 0.f;
    #pragma unroll
    for (int rt = 0; rt < 4; ++rt)
      #pragma unroll
      for (int rg = 0; rg < 4; ++rg)
        pa += sInv[rt * 16 + g * 4 + rg] * accP[rt][dt][rg];
    pa += __shfl_xor(pa, 16);
    pa += __shfl_xor(pa, 32);
    if (g == 0) sPool[w * 48 + dt * 16 + lam] = pa;   // unique writer per d
  }
  __syncthreads();
  if (t < DD) {
    float* ac = accum + ((size_t)side * BB + b) * 2 * DD;
    float ps = 0.f;
    const float* sp = selfb + t;
    #pragma unroll 4
    for (int r = 0; r < QB; ++r) ps = fmaf(sInv[r], sp[(size_t)r * DD], ps);
    atomicAdd(&ac[t], ps);
    atomicAdd(&ac[DD + t], sPool[t]);
  }
}

// ---------------- Finalize: divide by mask count, final l2norm ----------------
__global__ __launch_bounds__(256) void finalize_kernel(
    const float* __restrict__ accum, const int* __restrict__ qm,
    const int* __restrict__ am, float* __restrict__ out)
{
  const int b    = blockIdx.x & (BB - 1);
  const int side = blockIdx.x >> 7;
  const int* msk = side ? am : qm;
  const int t = threadIdx.x;
  __shared__ float red[8];

  float c = (float)msk[(size_t)b * LL + t];
  #pragma unroll
  for (int off = 1; off < 64; off <<= 1) c += __shfl_xor(c, off);
  if ((t & 63) == 0) red[t >> 6] = c;
  __syncthreads();
  float cnt = fmaxf(red[0] + red[1] + red[2] + red[3], 1e-9f);

  const float* ac = accum + ((size_t)side * BB + b) * 2 * DD;
  float v[3];
  float ssq = 0.f;
  #pragma unroll
  for (int i = 0; i < 3; ++i) {
    v[i] = ac[t * 3 + i] / cnt;
    ssq += v[i] * v[i];
  }
  #pragma unroll
  for (int off = 1; off < 64; off <<= 1) ssq += __shfl_xor(ssq, off);
  __syncthreads();
  if ((t & 63) == 0) red[t >> 6] = ssq;
  __syncthreads();
  float n = sqrtf(red[0] + red[1] + red[2] + red[3]);
  float inv = 1.f / fmaxf(n, 1e-12f);
  float* ob = out + ((size_t)side * BB + b) * 2 * DD;
  #pragma unroll
  for (int i = 0; i < 3; ++i) ob[t * 3 + i] = v[i] * inv;
}

extern "C" void kernel_launch(void* const* d_in, const int* in_sizes, int n_in,
                              void* d_out, int out_size, void* d_ws, size_t ws_size,
                              hipStream_t stream) {
  const float* qf = (const float*)d_in[0];
  const float* af = (const float*)d_in[1];
  const int*   qm = (const int*)d_in[2];
  const int*   am = (const int*)d_in[3];
  float* out   = (float*)d_out;
  float* accum = (float*)d_ws;   // 2*128*768*4 = 786 KB

  (void)hipMemsetAsync(accum, 0, sizeof(float) * 2 * BB * 2 * DD, stream);
  fused_kernel<<<dim3(1024), 512, 0, stream>>>(qf, af, qm, am, accum);
  finalize_kernel<<<256, 256, 0, stream>>>(accum, qm, am, out);
}